// Round 7
// baseline (237.245 us; speedup 1.0000x reference)
//
#include <hip/hip_runtime.h>
#include <hip/hip_bf16.h>

// ---------------------------------------------------------------------------
// Qwen2VL SDPA attention block, MI355X/gfx950. fp32 in/out, bf16 MFMA inside.
// T=4096, D=1280, H=16, HD=80, 8 segments of 512 (block-diagonal attention).
// Pipeline: [C]  convert hidden/qkv_w/proj_w fp32->bf16 (one fused kernel)
//           [K1] qkv GEMM (128x192 tile, dbuf global_load_lds, 3 blocks/CU);
//                epilogue scatters Q/K->[h][t][96], V->Vt[h][d][t]
//           [K2] rope(Qh,Kh) in place, vectorized (+1/sqrt(80) into q)
//           [K3] attention: 48KB LDS (3 blocks/CU), K dbuf + single-buf V
//           [K4] out = attn @ proj_w^T + proj_b (BM=64 tiles, 640 blocks)
// ---------------------------------------------------------------------------

#define T_DIM 4096
#define D_DIM 1280
#define NH    16
#define HD    80
#define HDP   96      // head dim padded to 3x32 for K=32 MFMA steps
#define SEG   512
#define VLP   136     // P LDS row stride (pad off pow2)

typedef __bf16 bf16;
typedef bf16  bf16x4 __attribute__((ext_vector_type(4)));
typedef bf16  bf16x8 __attribute__((ext_vector_type(8)));
typedef float f32x4  __attribute__((ext_vector_type(4)));

__device__ __forceinline__ void gload16(const bf16* g, bf16* l) {
  __builtin_amdgcn_global_load_lds(
      (const __attribute__((address_space(1))) void*)g,
      (__attribute__((address_space(3))) void*)l, 16, 0, 0);
}

// ---------------------------------------------------------------------------
// Fused fp32->bf16 convert of hidden (1310720 f4), qkv_w (1228800 f4),
// proj_w (409600 f4). Grid covers 2949120 float4 groups.
// ---------------------------------------------------------------------------
__global__ __launch_bounds__(256) void cvt_all(
    const float* __restrict__ hid, const float* __restrict__ qw,
    const float* __restrict__ pw, bf16* __restrict__ hb,
    bf16* __restrict__ qwb, bf16* __restrict__ pwb)
{
  int i = blockIdx.x * 256 + threadIdx.x;
  const float* src; bf16* dst; int off;
  if (i < 1310720)      { src = hid; dst = hb;  off = i; }
  else if (i < 2539520) { src = qw;  dst = qwb; off = i - 1310720; }
  else                  { src = pw;  dst = pwb; off = i - 2539520; }
  float4 v = ((const float4*)src)[off];
  ((bf16x4*)dst)[off] = (bf16x4){(bf16)v.x, (bf16)v.y, (bf16)v.z, (bf16)v.w};
}

// ---------------------------------------------------------------------------
// BMxBN-tile GEMM: C = A[M,K] @ W[N,K]^T + bias. BK=32, 4 waves (2x2), each
// wave (BM/2)x(BN/2). Double-buffered LDS via global_load_lds width=16.
// EPI=0 (BM=128,BN=192): 78 FLOP/staged-byte; scatter Q/K -> [h][t][HDP],
//        V -> Vt[h][d][T] (bf16x4 packed). EPI=1: row-major fp32 store.
// ---------------------------------------------------------------------------
template <int EPI, int BM, int BN>
__global__ __launch_bounds__(256, (EPI == 0) ? 3 : 4) void gemm128(
    const bf16* __restrict__ A, const bf16* __restrict__ W,
    const float* __restrict__ bias, void* __restrict__ out0,
    bf16* __restrict__ Kh, bf16* __restrict__ Vt,
    int N, int K, int tiles_n)
{
  constexpr int MI = BM / 32;               // m-frags per wave
  constexpr int NJ = BN / 32;               // n-frags per wave
  __shared__ __align__(16) bf16 As[2][BM * 32];
  __shared__ __align__(16) bf16 Bs[2][BN * 32];

  int tid  = threadIdx.x;
  int wave = tid >> 6, lane = tid & 63;
  int l15 = lane & 15, quad = lane >> 4, q8 = quad * 8;
  int mt, nt;
  if (EPI == 0) {
    // band swizzle: bands of 8 mt; within a band sweep nt; lin&7 ~ XCD
    int band = blockIdx.x / (8 * tiles_n);
    int r    = blockIdx.x % (8 * tiles_n);
    nt = r >> 3;
    mt = band * 8 + (r & 7);
  } else {
    mt = blockIdx.x / tiles_n;
    nt = blockIdx.x % tiles_n;
  }
  int m0 = mt * BM, n0 = nt * BN;
  int wm = (wave >> 1) * (BM / 2), wn = (wave & 1) * (BN / 2);

  int er  = tid >> 2;
  int ec8 = (tid & 3) * 8;
  const bf16* ga = A + (size_t)(m0 + er) * K + ec8;
  const bf16* gb = W + (size_t)(n0 + er) * K + ec8;

  auto issue = [&](int k, int p) {
    bf16* la = As[p] + tid * 8;
    bf16* lb = Bs[p] + tid * 8;
#pragma unroll
    for (int i = 0; i < BM / 64; ++i) gload16(ga + (size_t)i * 64 * K + k, la + i * 2048);
#pragma unroll
    for (int i = 0; i < BN / 64; ++i) gload16(gb + (size_t)i * 64 * K + k, lb + i * 2048);
  };

  f32x4 acc[MI][NJ];
#pragma unroll
  for (int i = 0; i < MI; ++i)
#pragma unroll
    for (int j = 0; j < NJ; ++j) acc[i][j] = (f32x4){0.f, 0.f, 0.f, 0.f};

  int NK = K / 32;
  issue(0, 0);
  for (int kt = 0; kt < NK; ++kt) {
    int p = kt & 1;
    __syncthreads();                      // drains DMA(kt) + prev frag reads
    if (kt + 1 < NK) issue((kt + 1) * 32, p ^ 1);
    bf16x8 af[MI], bfr[NJ];
#pragma unroll
    for (int i = 0; i < MI; ++i)
      af[i] = *(const bf16x8*)(As[p] + (wm + i * 16 + l15) * 32 + q8);
#pragma unroll
    for (int j = 0; j < NJ; ++j)
      bfr[j] = *(const bf16x8*)(Bs[p] + (wn + j * 16 + l15) * 32 + q8);
#pragma unroll
    for (int i = 0; i < MI; ++i)
#pragma unroll
      for (int j = 0; j < NJ; ++j)
        acc[i][j] = __builtin_amdgcn_mfma_f32_16x16x32_bf16(af[i], bfr[j], acc[i][j], 0, 0, 0);
  }

  if (EPI == 0) {
    bf16* Qh = (bf16*)out0;
#pragma unroll
    for (int j = 0; j < NJ; ++j) {
      int c = n0 + wn + j * 16 + l15;
      float bv = bias[c];
      int sel = c / D_DIM;             // 0=Q, 1=K, 2=V (16-col group never straddles)
      int cc  = c - sel * D_DIM;
      int h   = cc / HD;
      int d   = cc - h * HD;
      if (sel < 2) {
        bf16* base = (sel == 0) ? Qh : Kh;
#pragma unroll
        for (int i = 0; i < MI; ++i)
#pragma unroll
          for (int r = 0; r < 4; ++r) {
            int t = m0 + wm + i * 16 + quad * 4 + r;
            base[((size_t)h * T_DIM + t) * HDP + d] = (bf16)(acc[i][j][r] + bv);
          }
      } else {
        bf16* vrow = Vt + ((size_t)h * HD + d) * T_DIM;
#pragma unroll
        for (int i = 0; i < MI; ++i) {
          int t0 = m0 + wm + i * 16 + quad * 4;
          bf16x4 pv = {(bf16)(acc[i][j][0] + bv), (bf16)(acc[i][j][1] + bv),
                       (bf16)(acc[i][j][2] + bv), (bf16)(acc[i][j][3] + bv)};
          *(bf16x4*)(vrow + t0) = pv;
        }
      }
    }
  } else {
    float* out = (float*)out0;
#pragma unroll
    for (int j = 0; j < NJ; ++j) {
      int col = n0 + wn + j * 16 + l15;
      float bv = bias[col];
#pragma unroll
      for (int i = 0; i < MI; ++i)
#pragma unroll
        for (int r = 0; r < 4; ++r) {
          int row = m0 + wm + i * 16 + quad * 4 + r;
          out[(size_t)row * N + col] = acc[i][j][r] + bv;
        }
    }
  }
}

// ---------------------------------------------------------------------------
// K2: vectorized in-place RoPE on Qh/Kh + zero-pad cols 80..95.
// 6 slices per (h,t) row: slices 0..4 = 8 rotate pairs each, slice 5 = pad.
// ---------------------------------------------------------------------------
__global__ __launch_bounds__(256) void rope2(
    const float* __restrict__ rot, bf16* __restrict__ Qh, bf16* __restrict__ Kh)
{
  int gid = blockIdx.x * 256 + threadIdx.x;   // < 393216 = 65536 rows * 6
  int s   = gid % 6;
  int row = gid / 6;            // h*4096 + t
  int t   = row & (T_DIM - 1);
  bf16* qp = Qh + (size_t)row * HDP;
  bf16* kp = Kh + (size_t)row * HDP;
  const float scale = 0.11180339887498949f;  // 1/sqrt(80)

  if (s == 5) {
    bf16x8 z = {};
    *(bf16x8*)(qp + 80) = z; *(bf16x8*)(qp + 88) = z;
    *(bf16x8*)(kp + 80) = z; *(bf16x8*)(kp + 88) = z;
    return;
  }
  int i8 = s * 8;
  float4 f0 = *(const float4*)(rot + t * 40 + i8);
  float4 f1 = *(const float4*)(rot + t * 40 + i8 + 4);
  float fr[8] = {f0.x, f0.y, f0.z, f0.w, f1.x, f1.y, f1.z, f1.w};
  bf16x8 q1 = *(bf16x8*)(qp + i8), q2 = *(bf16x8*)(qp + i8 + 40);
  bf16x8 k1 = *(bf16x8*)(kp + i8), k2 = *(bf16x8*)(kp + i8 + 40);
  bf16x8 o1, o2, p1, p2;
#pragma unroll
  for (int j = 0; j < 8; ++j) {
    float c, sn;
    __sincosf(fr[j], &sn, &c);
    float a1 = (float)q1[j], a2 = (float)q2[j];
    o1[j] = (bf16)((a1 * c - a2 * sn) * scale);
    o2[j] = (bf16)((a2 * c + a1 * sn) * scale);
    float b1 = (float)k1[j], b2 = (float)k2[j];
    p1[j] = (bf16)(b1 * c - b2 * sn);
    p2[j] = (bf16)(b2 * c + b1 * sn);
  }
  *(bf16x8*)(qp + i8) = o1; *(bf16x8*)(qp + i8 + 40) = o2;
  *(bf16x8*)(kp + i8) = p1; *(bf16x8*)(kp + i8 + 40) = p2;
}

// ---------------------------------------------------------------------------
// K3: attention. Grid 1024 XCD-swizzled blocks (lin%8 groups share K/V L2).
// 48 KB LDS -> 3 blocks/CU. Phase A: K chunks double-buffered (R0/R1), one
// barrier per chunk; V(0) DMA issued during the last QK chunk. Phase B: V
// single-buffered in R0 (P overlays R1); V(kc+1) issued after the barrier
// that retires V(kc)'s MFMA reads. V chunks XOR-swizzled (chunk ^ (d&7)).
// ---------------------------------------------------------------------------
__global__ __launch_bounds__(256, 3) void attn_kernel(
    const bf16* __restrict__ Qh, const bf16* __restrict__ Kh,
    const bf16* __restrict__ Vt, bf16* __restrict__ out)
{
  __shared__ __align__(16) char smem[49152];
  bf16* KV[2] = {(bf16*)smem, (bf16*)(smem + 24576)};
  bf16* Pl    = (bf16*)(smem + 24576);   // phase B: P overlays R1 (17408 B)

  int lin  = blockIdx.x;
  int g    = lin & 127;        // (seg,head) group
  int tile = lin >> 7;         // 0..7
  int h    = g & 15;
  int seg  = g >> 4;
  int seg0 = seg * SEG;
  int t0   = seg0 + tile * 64;

  int tid  = threadIdx.x;
  int wave = tid >> 6;
  int lane = tid & 63;
  int l15 = lane & 15, quad = lane >> 4, q8 = quad * 8;
  int tw = t0 + wave * 16;

  const bf16* khbase = Kh + ((size_t)h * T_DIM + seg0) * HDP;
  const bf16* vtbase = Vt + (size_t)h * HD * T_DIM + seg0;

  auto issueK = [&](int kc, bf16* buf) {
    const bf16* src = khbase + (size_t)kc * (128 * HDP);
#pragma unroll
    for (int i = 0; i < 6; ++i)
      gload16(src + (i * 256 + tid) * 8, buf + (i * 256 + tid) * 8);
  };
  auto issueV = [&](int kc, bf16* buf) {
    const bf16* src = vtbase + kc * 128;
#pragma unroll
    for (int i = 0; i < 5; ++i) {
      int idx = i * 256 + tid;            // 0..1279
      int d = idx >> 4, ch = idx & 15;
      int chg = ch ^ (d & 7);             // XOR source-chunk swizzle
      gload16(src + (size_t)d * T_DIM + chg * 8, buf + idx * 8);
    }
  };

  issueK(0, KV[0]);

  bf16x8 qf[3];
  {
    const bf16* qbase = Qh + ((size_t)h * T_DIM + tw + l15) * HDP + q8;
#pragma unroll
    for (int kk = 0; kk < 3; ++kk) qf[kk] = *(const bf16x8*)(qbase + kk * 32);
  }

  // ---- Phase A: S = Q K^T, 4 chunks of 128 keys, 1 barrier/chunk ----
  f32x4 S[4][8];
  for (int kc = 0; kc < 4; ++kc) {
    bf16* buf = KV[kc & 1];
    __syncthreads();                       // drains DMA(kc) + prior reads
    if (kc < 3) issueK(kc + 1, KV[(kc & 1) ^ 1]);
    else        issueV(0, KV[0]);          // R0 free (its K chunk retired)
#pragma unroll
    for (int j = 0; j < 8; ++j) {
      f32x4 acc = {0.f, 0.f, 0.f, 0.f};
      const bf16* kb = buf + (j * 16 + l15) * HDP + q8;
#pragma unroll
      for (int kk = 0; kk < 3; ++kk)
        acc = __builtin_amdgcn_mfma_f32_16x16x32_bf16(qf[kk], *(const bf16x8*)(kb + kk * 32), acc, 0, 0, 0);
      S[kc][j] = acc;
    }
  }

  // ---- Softmax (exact; scale pre-folded into Q). V(0) in flight. ----
  float vsum[4];
#pragma unroll
  for (int r = 0; r < 4; ++r) {
    float m = -1e30f;
#pragma unroll
    for (int kc = 0; kc < 4; ++kc)
#pragma unroll
      for (int j = 0; j < 8; ++j) m = fmaxf(m, S[kc][j][r]);
    for (int off = 1; off < 16; off <<= 1) m = fmaxf(m, __shfl_xor(m, off));
    float s = 0.f;
#pragma unroll
    for (int kc = 0; kc < 4; ++kc)
#pragma unroll
      for (int j = 0; j < 8; ++j) {
        float e = __expf(S[kc][j][r] - m);
        S[kc][j][r] = e;
        s += e;
      }
    for (int off = 1; off < 16; off <<= 1) s += __shfl_xor(s, off);
    vsum[r] = s;
  }

  // ---- Phase B: O = P V, 4 chunks, single-buffered V in R0, P in R1 ----
  f32x4 O[5];
#pragma unroll
  for (int n = 0; n < 5; ++n) O[n] = (f32x4){0.f, 0.f, 0.f, 0.f};
  bf16* Plw = Pl + wave * (16 * VLP);
  bf16* vbuf = KV[0];

  __syncthreads();   // phase-A reads of R1 done; V(0) drained
  for (int kc = 0; kc < 4; ++kc) {
#pragma unroll
    for (int j = 0; j < 8; ++j)
#pragma unroll
      for (int r = 0; r < 4; ++r)
        Plw[(quad * 4 + r) * VLP + j * 16 + l15] = (bf16)S[kc][j][r];
    __syncthreads();                       // P(kc) visible; V(kc) drained
#pragma unroll
    for (int ks = 0; ks < 4; ++ks) {
      bf16x8 pa = *(const bf16x8*)(Plw + l15 * VLP + ks * 32 + q8);
#pragma unroll
      for (int n = 0; n < 5; ++n) {
        int d = n * 16 + l15;
        // global chunk (ks*4+quad) lives at LDS chunk ^(d&7)
        int chl = (ks * 4 + quad) ^ (d & 7);
        bf16x8 vb = *(const bf16x8*)(vbuf + d * 128 + chl * 8);
        O[n] = __builtin_amdgcn_mfma_f32_16x16x32_bf16(pa, vb, O[n], 0, 0, 0);
      }
    }
    if (kc < 3) {
      __syncthreads();                     // V(kc) MFMA reads done
      issueV(kc + 1, vbuf);
    }
  }

#pragma unroll
  for (int n = 0; n < 5; ++n)
#pragma unroll
    for (int r = 0; r < 4; ++r) {
      int row = tw + quad * 4 + r;
      int col = h * HD + n * 16 + l15;
      out[(size_t)row * D_DIM + col] = (bf16)(O[n][r] / vsum[r]);
    }
}

// ---------------------------------------------------------------------------
extern "C" void kernel_launch(void* const* d_in, const int* in_sizes, int n_in,
                              void* d_out, int out_size, void* d_ws, size_t ws_size,
                              hipStream_t stream)
{
  const float* hidden = (const float*)d_in[0];
  // d_in[1]: cu_seqlens (int32) — fixed 8x512 segments, handled structurally
  const float* rot    = (const float*)d_in[2];
  const float* qkv_w  = (const float*)d_in[3];
  const float* qkv_b  = (const float*)d_in[4];
  const float* proj_w = (const float*)d_in[5];
  const float* proj_b = (const float*)d_in[6];
  float* out = (float*)d_out;

  char* ws = (char*)d_ws;
  bf16* qkvw_bf  = (bf16*)(ws);              //  9,830,400 B [3840][1280]
  bf16* projw_bf = (bf16*)(ws +  9830400);   //  3,276,800 B [1280][1280]
  bf16* hid_bf   = (bf16*)(ws + 13107200);   // 10,485,760 B [4096][1280]
  bf16* attn     = (bf16*)(ws + 13107200);   // reuses hid_bf (dead after K1)
  bf16* Qh       = (bf16*)(ws + 23592960);   // 12,582,912 B [16][4096][96]
  bf16* Kh       = (bf16*)(ws + 36175872);   // 12,582,912 B
  bf16* Vt       = (bf16*)(ws + 48758784);   // 10,485,760 B [16][80][4096]
                                             // total 59,244,544 B

  cvt_all<<<dim3(11520), dim3(256), 0, stream>>>(
      hidden, qkv_w, proj_w, hid_bf, qkvw_bf, projw_bf);
  // K1: qkv GEMM, 32x20 tiles of 128x192, band-swizzled
  gemm128<0, 128, 192><<<dim3(640), dim3(256), 0, stream>>>(
      hid_bf, qkvw_bf, qkv_b, (void*)Qh, Kh, Vt, 3840, 1280, 20);
  // K2: rope (65536 rows x 6 slices)
  rope2<<<dim3(1536), dim3(256), 0, stream>>>(rot, Qh, Kh);
  // K3: block-diagonal attention, XCD-swizzled linear grid
  attn_kernel<<<dim3(1024), dim3(256), 0, stream>>>(Qh, Kh, Vt, attn);
  // K4: proj GEMM, 64x10 tiles of 64x128, fp32 out
  gemm128<1, 64, 128><<<dim3(640), dim3(256), 0, stream>>>(
      attn, projw_bf, proj_b, (void*)out, nullptr, nullptr, 1280, 1280, 10);
}

// Round 8
// 221.862 us; speedup vs baseline: 1.0693x; 1.0693x over previous
//
#include <hip/hip_runtime.h>
#include <hip/hip_bf16.h>

// ---------------------------------------------------------------------------
// Qwen2VL SDPA attention block, MI355X/gfx950. fp32 in/out, bf16 MFMA inside.
// T=4096, D=1280, H=16, HD=80, 8 segments of 512 (block-diagonal attention).
// Pipeline: [C]  convert hidden/qkv_w/proj_w fp32->bf16 (one fused kernel)
//           [K1] qkv GEMM (128x192 tile, dbuf global_load_lds, 3 blocks/CU);
//                epilogue scatters Q/K->[h][t][96], V->Vt[h][d][t]
//           [K2] rope(Qh,Kh) in place, vectorized (+1/sqrt(80) into q)
//           [K3] attention: K/V DMA double-buffered (R5 structure), exact
//                softmax, XCD-swizzled grid
//           [K4] out = attn @ proj_w^T + proj_b (BM=64 tiles, 640 blocks)
// ---------------------------------------------------------------------------

#define T_DIM 4096
#define D_DIM 1280
#define NH    16
#define HD    80
#define HDP   96      // head dim padded to 3x32 for K=32 MFMA steps
#define SEG   512
#define VLP   136     // P LDS row stride (pad off pow2)

typedef __bf16 bf16;
typedef bf16  bf16x4 __attribute__((ext_vector_type(4)));
typedef bf16  bf16x8 __attribute__((ext_vector_type(8)));
typedef float f32x4  __attribute__((ext_vector_type(4)));

__device__ __forceinline__ void gload16(const bf16* g, bf16* l) {
  __builtin_amdgcn_global_load_lds(
      (const __attribute__((address_space(1))) void*)g,
      (__attribute__((address_space(3))) void*)l, 16, 0, 0);
}

// ---------------------------------------------------------------------------
// Fused fp32->bf16 convert of hidden (1310720 f4), qkv_w (1228800 f4),
// proj_w (409600 f4). Grid covers 2949120 float4 groups.
// ---------------------------------------------------------------------------
__global__ __launch_bounds__(256) void cvt_all(
    const float* __restrict__ hid, const float* __restrict__ qw,
    const float* __restrict__ pw, bf16* __restrict__ hb,
    bf16* __restrict__ qwb, bf16* __restrict__ pwb)
{
  int i = blockIdx.x * 256 + threadIdx.x;
  const float* src; bf16* dst; int off;
  if (i < 1310720)      { src = hid; dst = hb;  off = i; }
  else if (i < 2539520) { src = qw;  dst = qwb; off = i - 1310720; }
  else                  { src = pw;  dst = pwb; off = i - 2539520; }
  float4 v = ((const float4*)src)[off];
  ((bf16x4*)dst)[off] = (bf16x4){(bf16)v.x, (bf16)v.y, (bf16)v.z, (bf16)v.w};
}

// ---------------------------------------------------------------------------
// BMxBN-tile GEMM: C = A[M,K] @ W[N,K]^T + bias. BK=32, 4 waves (2x2), each
// wave (BM/2)x(BN/2). Double-buffered LDS via global_load_lds width=16.
// EPI=0 (BM=128,BN=192): 78 FLOP/staged-byte; scatter Q/K -> [h][t][HDP],
//        V -> Vt[h][d][T] (bf16x4 packed). EPI=1: row-major fp32 store.
// ---------------------------------------------------------------------------
template <int EPI, int BM, int BN>
__global__ __launch_bounds__(256, (EPI == 0) ? 3 : 4) void gemm128(
    const bf16* __restrict__ A, const bf16* __restrict__ W,
    const float* __restrict__ bias, void* __restrict__ out0,
    bf16* __restrict__ Kh, bf16* __restrict__ Vt,
    int N, int K, int tiles_n)
{
  constexpr int MI = BM / 32;               // m-frags per wave
  constexpr int NJ = BN / 32;               // n-frags per wave
  __shared__ __align__(16) bf16 As[2][BM * 32];
  __shared__ __align__(16) bf16 Bs[2][BN * 32];

  int tid  = threadIdx.x;
  int wave = tid >> 6, lane = tid & 63;
  int l15 = lane & 15, quad = lane >> 4, q8 = quad * 8;
  int mt, nt;
  if (EPI == 0) {
    // band swizzle: bands of 8 mt; within a band sweep nt; lin&7 ~ XCD
    int band = blockIdx.x / (8 * tiles_n);
    int r    = blockIdx.x % (8 * tiles_n);
    nt = r >> 3;
    mt = band * 8 + (r & 7);
  } else {
    mt = blockIdx.x / tiles_n;
    nt = blockIdx.x % tiles_n;
  }
  int m0 = mt * BM, n0 = nt * BN;
  int wm = (wave >> 1) * (BM / 2), wn = (wave & 1) * (BN / 2);

  int er  = tid >> 2;
  int ec8 = (tid & 3) * 8;
  const bf16* ga = A + (size_t)(m0 + er) * K + ec8;
  const bf16* gb = W + (size_t)(n0 + er) * K + ec8;

  auto issue = [&](int k, int p) {
    bf16* la = As[p] + tid * 8;
    bf16* lb = Bs[p] + tid * 8;
#pragma unroll
    for (int i = 0; i < BM / 64; ++i) gload16(ga + (size_t)i * 64 * K + k, la + i * 2048);
#pragma unroll
    for (int i = 0; i < BN / 64; ++i) gload16(gb + (size_t)i * 64 * K + k, lb + i * 2048);
  };

  f32x4 acc[MI][NJ];
#pragma unroll
  for (int i = 0; i < MI; ++i)
#pragma unroll
    for (int j = 0; j < NJ; ++j) acc[i][j] = (f32x4){0.f, 0.f, 0.f, 0.f};

  int NK = K / 32;
  issue(0, 0);
  for (int kt = 0; kt < NK; ++kt) {
    int p = kt & 1;
    __syncthreads();                      // drains DMA(kt) + prev frag reads
    if (kt + 1 < NK) issue((kt + 1) * 32, p ^ 1);
    bf16x8 af[MI], bfr[NJ];
#pragma unroll
    for (int i = 0; i < MI; ++i)
      af[i] = *(const bf16x8*)(As[p] + (wm + i * 16 + l15) * 32 + q8);
#pragma unroll
    for (int j = 0; j < NJ; ++j)
      bfr[j] = *(const bf16x8*)(Bs[p] + (wn + j * 16 + l15) * 32 + q8);
#pragma unroll
    for (int i = 0; i < MI; ++i)
#pragma unroll
      for (int j = 0; j < NJ; ++j)
        acc[i][j] = __builtin_amdgcn_mfma_f32_16x16x32_bf16(af[i], bfr[j], acc[i][j], 0, 0, 0);
  }

  if (EPI == 0) {
    bf16* Qh = (bf16*)out0;
#pragma unroll
    for (int j = 0; j < NJ; ++j) {
      int c = n0 + wn + j * 16 + l15;
      float bv = bias[c];
      int sel = c / D_DIM;             // 0=Q, 1=K, 2=V (16-col group never straddles)
      int cc  = c - sel * D_DIM;
      int h   = cc / HD;
      int d   = cc - h * HD;
      if (sel < 2) {
        bf16* base = (sel == 0) ? Qh : Kh;
#pragma unroll
        for (int i = 0; i < MI; ++i)
#pragma unroll
          for (int r = 0; r < 4; ++r) {
            int t = m0 + wm + i * 16 + quad * 4 + r;
            base[((size_t)h * T_DIM + t) * HDP + d] = (bf16)(acc[i][j][r] + bv);
          }
      } else {
        bf16* vrow = Vt + ((size_t)h * HD + d) * T_DIM;
#pragma unroll
        for (int i = 0; i < MI; ++i) {
          int t0 = m0 + wm + i * 16 + quad * 4;
          bf16x4 pv = {(bf16)(acc[i][j][0] + bv), (bf16)(acc[i][j][1] + bv),
                       (bf16)(acc[i][j][2] + bv), (bf16)(acc[i][j][3] + bv)};
          *(bf16x4*)(vrow + t0) = pv;
        }
      }
    }
  } else {
    float* out = (float*)out0;
#pragma unroll
    for (int j = 0; j < NJ; ++j) {
      int col = n0 + wn + j * 16 + l15;
      float bv = bias[col];
#pragma unroll
      for (int i = 0; i < MI; ++i)
#pragma unroll
        for (int r = 0; r < 4; ++r) {
          int row = m0 + wm + i * 16 + quad * 4 + r;
          out[(size_t)row * N + col] = acc[i][j][r] + bv;
        }
    }
  }
}

// ---------------------------------------------------------------------------
// K2: vectorized in-place RoPE on Qh/Kh + zero-pad cols 80..95.
// 6 slices per (h,t) row: slices 0..4 = 8 rotate pairs each, slice 5 = pad.
// ---------------------------------------------------------------------------
__global__ __launch_bounds__(256) void rope2(
    const float* __restrict__ rot, bf16* __restrict__ Qh, bf16* __restrict__ Kh)
{
  int gid = blockIdx.x * 256 + threadIdx.x;   // < 393216 = 65536 rows * 6
  int s   = gid % 6;
  int row = gid / 6;            // h*4096 + t
  int t   = row & (T_DIM - 1);
  bf16* qp = Qh + (size_t)row * HDP;
  bf16* kp = Kh + (size_t)row * HDP;
  const float scale = 0.11180339887498949f;  // 1/sqrt(80)

  if (s == 5) {
    bf16x8 z = {};
    *(bf16x8*)(qp + 80) = z; *(bf16x8*)(qp + 88) = z;
    *(bf16x8*)(kp + 80) = z; *(bf16x8*)(kp + 88) = z;
    return;
  }
  int i8 = s * 8;
  float4 f0 = *(const float4*)(rot + t * 40 + i8);
  float4 f1 = *(const float4*)(rot + t * 40 + i8 + 4);
  float fr[8] = {f0.x, f0.y, f0.z, f0.w, f1.x, f1.y, f1.z, f1.w};
  bf16x8 q1 = *(bf16x8*)(qp + i8), q2 = *(bf16x8*)(qp + i8 + 40);
  bf16x8 k1 = *(bf16x8*)(kp + i8), k2 = *(bf16x8*)(kp + i8 + 40);
  bf16x8 o1, o2, p1, p2;
#pragma unroll
  for (int j = 0; j < 8; ++j) {
    float c, sn;
    __sincosf(fr[j], &sn, &c);
    float a1 = (float)q1[j], a2 = (float)q2[j];
    o1[j] = (bf16)((a1 * c - a2 * sn) * scale);
    o2[j] = (bf16)((a2 * c + a1 * sn) * scale);
    float b1 = (float)k1[j], b2 = (float)k2[j];
    p1[j] = (bf16)(b1 * c - b2 * sn);
    p2[j] = (bf16)(b2 * c + b1 * sn);
  }
  *(bf16x8*)(qp + i8) = o1; *(bf16x8*)(qp + i8 + 40) = o2;
  *(bf16x8*)(kp + i8) = p1; *(bf16x8*)(kp + i8 + 40) = p2;
}

// ---------------------------------------------------------------------------
// K3: attention (R5 structure — measured best). Grid 1024 XCD-swizzled
// blocks (lin%8 groups share K/V L2). K/V staged via global_load_lds into
// double buffers; one barrier per QK chunk; V(0) prefetch issued during the
// last QK chunk and drains behind the softmax VALU stretch. V chunks
// XOR-swizzled (chunk ^ (d&7)) so [80][128] pow-2 stride reads stay at the
// bank floor.
// ---------------------------------------------------------------------------
__global__ __launch_bounds__(256, 2) void attn_kernel(
    const bf16* __restrict__ Qh, const bf16* __restrict__ Kh,
    const bf16* __restrict__ Vt, bf16* __restrict__ out)
{
  // KV double buffers 2 x 24576 B (K [128][96] / V [80][128]); P 17408 B
  __shared__ __align__(16) char smem[66560];
  bf16* KV[2] = {(bf16*)smem, (bf16*)(smem + 24576)};
  bf16* Pl    = (bf16*)(smem + 49152);

  int lin  = blockIdx.x;
  int g    = lin & 127;        // (seg,head) group
  int tile = lin >> 7;         // 0..7
  int h    = g & 15;
  int seg  = g >> 4;
  int seg0 = seg * SEG;
  int t0   = seg0 + tile * 64;

  int tid  = threadIdx.x;
  int wave = tid >> 6;
  int lane = tid & 63;
  int l15 = lane & 15, quad = lane >> 4, q8 = quad * 8;
  int tw = t0 + wave * 16;

  const bf16* khbase = Kh + ((size_t)h * T_DIM + seg0) * HDP;
  const bf16* vtbase = Vt + (size_t)h * HD * T_DIM + seg0;

  auto issueK = [&](int kc, bf16* buf) {
    const bf16* src = khbase + (size_t)kc * (128 * HDP);
#pragma unroll
    for (int i = 0; i < 6; ++i)
      gload16(src + (i * 256 + tid) * 8, buf + (i * 256 + tid) * 8);
  };
  auto issueV = [&](int kc, bf16* buf) {
    const bf16* src = vtbase + kc * 128;
#pragma unroll
    for (int i = 0; i < 5; ++i) {
      int idx = i * 256 + tid;            // 0..1279
      int d = idx >> 4, ch = idx & 15;
      int chg = ch ^ (d & 7);             // XOR source-chunk swizzle
      gload16(src + (size_t)d * T_DIM + chg * 8, buf + idx * 8);
    }
  };

  issueK(0, KV[0]);

  bf16x8 qf[3];
  {
    const bf16* qbase = Qh + ((size_t)h * T_DIM + tw + l15) * HDP + q8;
#pragma unroll
    for (int kk = 0; kk < 3; ++kk) qf[kk] = *(const bf16x8*)(qbase + kk * 32);
  }

  // ---- Phase A: S = Q K^T, 4 chunks of 128 keys, 1 barrier/chunk ----
  f32x4 S[4][8];
  for (int kc = 0; kc < 4; ++kc) {
    bf16* buf = KV[kc & 1];
    __syncthreads();                       // drains DMA(kc) + prior reads
    if (kc < 3) issueK(kc + 1, KV[(kc & 1) ^ 1]);
    else        issueV(0, KV[0]);          // KV[0] free (last read chunk 2)
#pragma unroll
    for (int j = 0; j < 8; ++j) {
      f32x4 acc = {0.f, 0.f, 0.f, 0.f};
      const bf16* kb = buf + (j * 16 + l15) * HDP + q8;
#pragma unroll
      for (int kk = 0; kk < 3; ++kk)
        acc = __builtin_amdgcn_mfma_f32_16x16x32_bf16(qf[kk], *(const bf16x8*)(kb + kk * 32), acc, 0, 0, 0);
      S[kc][j] = acc;
    }
  }

  // ---- Softmax (exact; scale pre-folded into Q). V(0) in flight. ----
  float vsum[4];
#pragma unroll
  for (int r = 0; r < 4; ++r) {
    float m = -1e30f;
#pragma unroll
    for (int kc = 0; kc < 4; ++kc)
#pragma unroll
      for (int j = 0; j < 8; ++j) m = fmaxf(m, S[kc][j][r]);
    for (int off = 1; off < 16; off <<= 1) m = fmaxf(m, __shfl_xor(m, off));
    float s = 0.f;
#pragma unroll
    for (int kc = 0; kc < 4; ++kc)
#pragma unroll
      for (int j = 0; j < 8; ++j) {
        float e = __expf(S[kc][j][r] - m);
        S[kc][j][r] = e;
        s += e;
      }
    for (int off = 1; off < 16; off <<= 1) s += __shfl_xor(s, off);
    vsum[r] = s;
  }

  // ---- Phase B: O = P V, 4 chunks, V prefetched one chunk ahead ----
  f32x4 O[5];
#pragma unroll
  for (int n = 0; n < 5; ++n) O[n] = (f32x4){0.f, 0.f, 0.f, 0.f};
  bf16* Plw = Pl + wave * (16 * VLP);

  for (int kc = 0; kc < 4; ++kc) {
    bf16* vbuf = KV[kc & 1];
    __syncthreads();                       // drains V(kc); prior MFMA reads done
    if (kc < 3) issueV(kc + 1, KV[(kc & 1) ^ 1]);
#pragma unroll
    for (int j = 0; j < 8; ++j)
#pragma unroll
      for (int r = 0; r < 4; ++r)
        Plw[(quad * 4 + r) * VLP + j * 16 + l15] = (bf16)S[kc][j][r];
    __syncthreads();                       // P visible
#pragma unroll
    for (int ks = 0; ks < 4; ++ks) {
      bf16x8 pa = *(const bf16x8*)(Plw + l15 * VLP + ks * 32 + q8);
#pragma unroll
      for (int n = 0; n < 5; ++n) {
        int d = n * 16 + l15;
        // global chunk (ks*4+quad) lives at LDS chunk ^(d&7)
        int chl = (ks * 4 + quad) ^ (d & 7);
        bf16x8 vb = *(const bf16x8*)(vbuf + d * 128 + chl * 8);
        O[n] = __builtin_amdgcn_mfma_f32_16x16x32_bf16(pa, vb, O[n], 0, 0, 0);
      }
    }
  }

#pragma unroll
  for (int n = 0; n < 5; ++n)
#pragma unroll
    for (int r = 0; r < 4; ++r) {
      int row = tw + quad * 4 + r;
      int col = h * HD + n * 16 + l15;
      out[(size_t)row * D_DIM + col] = (bf16)(O[n][r] / vsum[r]);
    }
}

// ---------------------------------------------------------------------------
extern "C" void kernel_launch(void* const* d_in, const int* in_sizes, int n_in,
                              void* d_out, int out_size, void* d_ws, size_t ws_size,
                              hipStream_t stream)
{
  const float* hidden = (const float*)d_in[0];
  // d_in[1]: cu_seqlens (int32) — fixed 8x512 segments, handled structurally
  const float* rot    = (const float*)d_in[2];
  const float* qkv_w  = (const float*)d_in[3];
  const float* qkv_b  = (const float*)d_in[4];
  const float* proj_w = (const float*)d_in[5];
  const float* proj_b = (const float*)d_in[6];
  float* out = (float*)d_out;

  char* ws = (char*)d_ws;
  bf16* qkvw_bf  = (bf16*)(ws);              //  9,830,400 B [3840][1280]
  bf16* projw_bf = (bf16*)(ws +  9830400);   //  3,276,800 B [1280][1280]
  bf16* hid_bf   = (bf16*)(ws + 13107200);   // 10,485,760 B [4096][1280]
  bf16* attn     = (bf16*)(ws + 13107200);   // reuses hid_bf (dead after K1)
  bf16* Qh       = (bf16*)(ws + 23592960);   // 12,582,912 B [16][4096][96]
  bf16* Kh       = (bf16*)(ws + 36175872);   // 12,582,912 B
  bf16* Vt       = (bf16*)(ws + 48758784);   // 10,485,760 B [16][80][4096]
                                             // total 59,244,544 B

  cvt_all<<<dim3(11520), dim3(256), 0, stream>>>(
      hidden, qkv_w, proj_w, hid_bf, qkvw_bf, projw_bf);
  // K1: qkv GEMM, 32x20 tiles of 128x192, band-swizzled
  gemm128<0, 128, 192><<<dim3(640), dim3(256), 0, stream>>>(
      hid_bf, qkvw_bf, qkv_b, (void*)Qh, Kh, Vt, 3840, 1280, 20);
  // K2: rope (65536 rows x 6 slices)
  rope2<<<dim3(1536), dim3(256), 0, stream>>>(rot, Qh, Kh);
  // K3: block-diagonal attention, XCD-swizzled linear grid
  attn_kernel<<<dim3(1024), dim3(256), 0, stream>>>(Qh, Kh, Vt, attn);
  // K4: proj GEMM, 64x10 tiles of 64x128, fp32 out
  gemm128<1, 64, 128><<<dim3(640), dim3(256), 0, stream>>>(
      attn, projw_bf, proj_b, (void*)out, nullptr, nullptr, 1280, 1280, 10);
}

// Round 9
// 214.756 us; speedup vs baseline: 1.1047x; 1.0331x over previous
//
#include <hip/hip_runtime.h>
#include <hip/hip_bf16.h>

// ---------------------------------------------------------------------------
// Qwen2VL SDPA attention block, MI355X/gfx950. fp32 in/out, bf16 MFMA inside.
// T=4096, D=1280, H=16, HD=80, 8 segments of 512 (block-diagonal attention).
// Pipeline: [C]  convert hidden/qkv_w/proj_w fp32->bf16 (one fused kernel)
//           [K1] qkv GEMM (128x192 tile, dbuf global_load_lds, 3 blocks/CU);
//                epilogue scatters Q/K->[h][t][96], V->Vt[h][d][t]
//           [K2] rope(Qh,Kh) in place, vectorized (+1/sqrt(80) into q)
//           [K3] attention: K/V DMA double-buffered (R5 structure), exact
//                softmax, XCD-swizzled grid
//           [K4] out = attn @ proj_w^T + proj_b (BM=64, A-sharing XCD swizzle)
// ---------------------------------------------------------------------------

#define T_DIM 4096
#define D_DIM 1280
#define NH    16
#define HD    80
#define HDP   96      // head dim padded to 3x32 for K=32 MFMA steps
#define SEG   512
#define VLP   136     // P LDS row stride (pad off pow2)

typedef __bf16 bf16;
typedef bf16  bf16x4 __attribute__((ext_vector_type(4)));
typedef bf16  bf16x8 __attribute__((ext_vector_type(8)));
typedef float f32x4  __attribute__((ext_vector_type(4)));

__device__ __forceinline__ void gload16(const bf16* g, bf16* l) {
  __builtin_amdgcn_global_load_lds(
      (const __attribute__((address_space(1))) void*)g,
      (__attribute__((address_space(3))) void*)l, 16, 0, 0);
}

// ---------------------------------------------------------------------------
// Fused fp32->bf16 convert of hidden (1310720 f4), qkv_w (1228800 f4),
// proj_w (409600 f4). Grid covers 2949120 float4 groups.
// ---------------------------------------------------------------------------
__global__ __launch_bounds__(256) void cvt_all(
    const float* __restrict__ hid, const float* __restrict__ qw,
    const float* __restrict__ pw, bf16* __restrict__ hb,
    bf16* __restrict__ qwb, bf16* __restrict__ pwb)
{
  int i = blockIdx.x * 256 + threadIdx.x;
  const float* src; bf16* dst; int off;
  if (i < 1310720)      { src = hid; dst = hb;  off = i; }
  else if (i < 2539520) { src = qw;  dst = qwb; off = i - 1310720; }
  else                  { src = pw;  dst = pwb; off = i - 2539520; }
  float4 v = ((const float4*)src)[off];
  ((bf16x4*)dst)[off] = (bf16x4){(bf16)v.x, (bf16)v.y, (bf16)v.z, (bf16)v.w};
}

// ---------------------------------------------------------------------------
// BMxBN-tile GEMM: C = A[M,K] @ W[N,K]^T + bias. BK=32, 4 waves (2x2), each
// wave (BM/2)x(BN/2). Double-buffered LDS via global_load_lds width=16.
// EPI=0 (BM=128,BN=192): band swizzle keeps one mt's nt-sweep on one XCD;
//        scatter Q/K -> [h][t][HDP], V -> Vt[h][d][T] (bf16x4 packed).
// EPI=1: A-sharing swizzle (mt = lin % tiles_m) so all nt-blocks of an
//        A-tile land on one XCD (lin%8 == mt%8); row-major fp32 store.
// ---------------------------------------------------------------------------
template <int EPI, int BM, int BN>
__global__ __launch_bounds__(256, (EPI == 0) ? 3 : 4) void gemm128(
    const bf16* __restrict__ A, const bf16* __restrict__ W,
    const float* __restrict__ bias, void* __restrict__ out0,
    bf16* __restrict__ Kh, bf16* __restrict__ Vt,
    int N, int K, int tiles_n)
{
  constexpr int MI = BM / 32;               // m-frags per wave
  constexpr int NJ = BN / 32;               // n-frags per wave
  __shared__ __align__(16) bf16 As[2][BM * 32];
  __shared__ __align__(16) bf16 Bs[2][BN * 32];

  int tid  = threadIdx.x;
  int wave = tid >> 6, lane = tid & 63;
  int l15 = lane & 15, quad = lane >> 4, q8 = quad * 8;
  int mt, nt;
  if (EPI == 0) {
    // band swizzle: bands of 8 mt; within a band sweep nt; lin&7 = mt-in-band
    // -> all nt-blocks sharing an A-tile have lin%8 == mt%8 (same XCD)
    int band = blockIdx.x / (8 * tiles_n);
    int r    = blockIdx.x % (8 * tiles_n);
    nt = r >> 3;
    mt = band * 8 + (r & 7);
  } else {
    // A-sharing swizzle: lin = nt*tiles_m + mt -> lin%8 == mt%8 (same XCD)
    int tiles_m = gridDim.x / tiles_n;
    mt = blockIdx.x % tiles_m;
    nt = blockIdx.x / tiles_m;
  }
  int m0 = mt * BM, n0 = nt * BN;
  int wm = (wave >> 1) * (BM / 2), wn = (wave & 1) * (BN / 2);

  int er  = tid >> 2;
  int ec8 = (tid & 3) * 8;
  const bf16* ga = A + (size_t)(m0 + er) * K + ec8;
  const bf16* gb = W + (size_t)(n0 + er) * K + ec8;

  auto issue = [&](int k, int p) {
    bf16* la = As[p] + tid * 8;
    bf16* lb = Bs[p] + tid * 8;
#pragma unroll
    for (int i = 0; i < BM / 64; ++i) gload16(ga + (size_t)i * 64 * K + k, la + i * 2048);
#pragma unroll
    for (int i = 0; i < BN / 64; ++i) gload16(gb + (size_t)i * 64 * K + k, lb + i * 2048);
  };

  f32x4 acc[MI][NJ];
#pragma unroll
  for (int i = 0; i < MI; ++i)
#pragma unroll
    for (int j = 0; j < NJ; ++j) acc[i][j] = (f32x4){0.f, 0.f, 0.f, 0.f};

  int NK = K / 32;
  issue(0, 0);
  for (int kt = 0; kt < NK; ++kt) {
    int p = kt & 1;
    __syncthreads();                      // drains DMA(kt) + prev frag reads
    if (kt + 1 < NK) issue((kt + 1) * 32, p ^ 1);
    bf16x8 af[MI], bfr[NJ];
#pragma unroll
    for (int i = 0; i < MI; ++i)
      af[i] = *(const bf16x8*)(As[p] + (wm + i * 16 + l15) * 32 + q8);
#pragma unroll
    for (int j = 0; j < NJ; ++j)
      bfr[j] = *(const bf16x8*)(Bs[p] + (wn + j * 16 + l15) * 32 + q8);
#pragma unroll
    for (int i = 0; i < MI; ++i)
#pragma unroll
      for (int j = 0; j < NJ; ++j)
        acc[i][j] = __builtin_amdgcn_mfma_f32_16x16x32_bf16(af[i], bfr[j], acc[i][j], 0, 0, 0);
  }

  if (EPI == 0) {
    bf16* Qh = (bf16*)out0;
#pragma unroll
    for (int j = 0; j < NJ; ++j) {
      int c = n0 + wn + j * 16 + l15;
      float bv = bias[c];
      int sel = c / D_DIM;             // 0=Q, 1=K, 2=V (16-col group never straddles)
      int cc  = c - sel * D_DIM;
      int h   = cc / HD;
      int d   = cc - h * HD;
      if (sel < 2) {
        bf16* base = (sel == 0) ? Qh : Kh;
#pragma unroll
        for (int i = 0; i < MI; ++i)
#pragma unroll
          for (int r = 0; r < 4; ++r) {
            int t = m0 + wm + i * 16 + quad * 4 + r;
            base[((size_t)h * T_DIM + t) * HDP + d] = (bf16)(acc[i][j][r] + bv);
          }
      } else {
        bf16* vrow = Vt + ((size_t)h * HD + d) * T_DIM;
#pragma unroll
        for (int i = 0; i < MI; ++i) {
          int t0 = m0 + wm + i * 16 + quad * 4;
          bf16x4 pv = {(bf16)(acc[i][j][0] + bv), (bf16)(acc[i][j][1] + bv),
                       (bf16)(acc[i][j][2] + bv), (bf16)(acc[i][j][3] + bv)};
          *(bf16x4*)(vrow + t0) = pv;
        }
      }
    }
  } else {
    float* out = (float*)out0;
#pragma unroll
    for (int j = 0; j < NJ; ++j) {
      int col = n0 + wn + j * 16 + l15;
      float bv = bias[col];
#pragma unroll
      for (int i = 0; i < MI; ++i)
#pragma unroll
        for (int r = 0; r < 4; ++r) {
          int row = m0 + wm + i * 16 + quad * 4 + r;
          out[(size_t)row * N + col] = acc[i][j][r] + bv;
        }
    }
  }
}

// ---------------------------------------------------------------------------
// K2: vectorized in-place RoPE on Qh/Kh + zero-pad cols 80..95.
// 6 slices per (h,t) row: slices 0..4 = 8 rotate pairs each, slice 5 = pad.
// ---------------------------------------------------------------------------
__global__ __launch_bounds__(256) void rope2(
    const float* __restrict__ rot, bf16* __restrict__ Qh, bf16* __restrict__ Kh)
{
  int gid = blockIdx.x * 256 + threadIdx.x;   // < 393216 = 65536 rows * 6
  int s   = gid % 6;
  int row = gid / 6;            // h*4096 + t
  int t   = row & (T_DIM - 1);
  bf16* qp = Qh + (size_t)row * HDP;
  bf16* kp = Kh + (size_t)row * HDP;
  const float scale = 0.11180339887498949f;  // 1/sqrt(80)

  if (s == 5) {
    bf16x8 z = {};
    *(bf16x8*)(qp + 80) = z; *(bf16x8*)(qp + 88) = z;
    *(bf16x8*)(kp + 80) = z; *(bf16x8*)(kp + 88) = z;
    return;
  }
  int i8 = s * 8;
  float4 f0 = *(const float4*)(rot + t * 40 + i8);
  float4 f1 = *(const float4*)(rot + t * 40 + i8 + 4);
  float fr[8] = {f0.x, f0.y, f0.z, f0.w, f1.x, f1.y, f1.z, f1.w};
  bf16x8 q1 = *(bf16x8*)(qp + i8), q2 = *(bf16x8*)(qp + i8 + 40);
  bf16x8 k1 = *(bf16x8*)(kp + i8), k2 = *(bf16x8*)(kp + i8 + 40);
  bf16x8 o1, o2, p1, p2;
#pragma unroll
  for (int j = 0; j < 8; ++j) {
    float c, sn;
    __sincosf(fr[j], &sn, &c);
    float a1 = (float)q1[j], a2 = (float)q2[j];
    o1[j] = (bf16)((a1 * c - a2 * sn) * scale);
    o2[j] = (bf16)((a2 * c + a1 * sn) * scale);
    float b1 = (float)k1[j], b2 = (float)k2[j];
    p1[j] = (bf16)(b1 * c - b2 * sn);
    p2[j] = (bf16)(b2 * c + b1 * sn);
  }
  *(bf16x8*)(qp + i8) = o1; *(bf16x8*)(qp + i8 + 40) = o2;
  *(bf16x8*)(kp + i8) = p1; *(bf16x8*)(kp + i8 + 40) = p2;
}

// ---------------------------------------------------------------------------
// K3: attention (R5 structure — measured best). Grid 1024 XCD-swizzled
// blocks (lin%8 groups share K/V L2). K/V staged via global_load_lds into
// double buffers; one barrier per QK chunk; V(0) prefetch issued during the
// last QK chunk and drains behind the softmax VALU stretch. V chunks
// XOR-swizzled (chunk ^ (d&7)) so [80][128] pow-2 stride reads stay at the
// bank floor.
// ---------------------------------------------------------------------------
__global__ __launch_bounds__(256, 2) void attn_kernel(
    const bf16* __restrict__ Qh, const bf16* __restrict__ Kh,
    const bf16* __restrict__ Vt, bf16* __restrict__ out)
{
  // KV double buffers 2 x 24576 B (K [128][96] / V [80][128]); P 17408 B
  __shared__ __align__(16) char smem[66560];
  bf16* KV[2] = {(bf16*)smem, (bf16*)(smem + 24576)};
  bf16* Pl    = (bf16*)(smem + 49152);

  int lin  = blockIdx.x;
  int g    = lin & 127;        // (seg,head) group
  int tile = lin >> 7;         // 0..7
  int h    = g & 15;
  int seg  = g >> 4;
  int seg0 = seg * SEG;
  int t0   = seg0 + tile * 64;

  int tid  = threadIdx.x;
  int wave = tid >> 6;
  int lane = tid & 63;
  int l15 = lane & 15, quad = lane >> 4, q8 = quad * 8;
  int tw = t0 + wave * 16;

  const bf16* khbase = Kh + ((size_t)h * T_DIM + seg0) * HDP;
  const bf16* vtbase = Vt + (size_t)h * HD * T_DIM + seg0;

  auto issueK = [&](int kc, bf16* buf) {
    const bf16* src = khbase + (size_t)kc * (128 * HDP);
#pragma unroll
    for (int i = 0; i < 6; ++i)
      gload16(src + (i * 256 + tid) * 8, buf + (i * 256 + tid) * 8);
  };
  auto issueV = [&](int kc, bf16* buf) {
    const bf16* src = vtbase + kc * 128;
#pragma unroll
    for (int i = 0; i < 5; ++i) {
      int idx = i * 256 + tid;            // 0..1279
      int d = idx >> 4, ch = idx & 15;
      int chg = ch ^ (d & 7);             // XOR source-chunk swizzle
      gload16(src + (size_t)d * T_DIM + chg * 8, buf + idx * 8);
    }
  };

  issueK(0, KV[0]);

  bf16x8 qf[3];
  {
    const bf16* qbase = Qh + ((size_t)h * T_DIM + tw + l15) * HDP + q8;
#pragma unroll
    for (int kk = 0; kk < 3; ++kk) qf[kk] = *(const bf16x8*)(qbase + kk * 32);
  }

  // ---- Phase A: S = Q K^T, 4 chunks of 128 keys, 1 barrier/chunk ----
  f32x4 S[4][8];
  for (int kc = 0; kc < 4; ++kc) {
    bf16* buf = KV[kc & 1];
    __syncthreads();                       // drains DMA(kc) + prior reads
    if (kc < 3) issueK(kc + 1, KV[(kc & 1) ^ 1]);
    else        issueV(0, KV[0]);          // KV[0] free (last read chunk 2)
#pragma unroll
    for (int j = 0; j < 8; ++j) {
      f32x4 acc = {0.f, 0.f, 0.f, 0.f};
      const bf16* kb = buf + (j * 16 + l15) * HDP + q8;
#pragma unroll
      for (int kk = 0; kk < 3; ++kk)
        acc = __builtin_amdgcn_mfma_f32_16x16x32_bf16(qf[kk], *(const bf16x8*)(kb + kk * 32), acc, 0, 0, 0);
      S[kc][j] = acc;
    }
  }

  // ---- Softmax (exact; scale pre-folded into Q). V(0) in flight. ----
  float vsum[4];
#pragma unroll
  for (int r = 0; r < 4; ++r) {
    float m = -1e30f;
#pragma unroll
    for (int kc = 0; kc < 4; ++kc)
#pragma unroll
      for (int j = 0; j < 8; ++j) m = fmaxf(m, S[kc][j][r]);
    for (int off = 1; off < 16; off <<= 1) m = fmaxf(m, __shfl_xor(m, off));
    float s = 0.f;
#pragma unroll
    for (int kc = 0; kc < 4; ++kc)
#pragma unroll
      for (int j = 0; j < 8; ++j) {
        float e = __expf(S[kc][j][r] - m);
        S[kc][j][r] = e;
        s += e;
      }
    for (int off = 1; off < 16; off <<= 1) s += __shfl_xor(s, off);
    vsum[r] = s;
  }

  // ---- Phase B: O = P V, 4 chunks, V prefetched one chunk ahead ----
  f32x4 O[5];
#pragma unroll
  for (int n = 0; n < 5; ++n) O[n] = (f32x4){0.f, 0.f, 0.f, 0.f};
  bf16* Plw = Pl + wave * (16 * VLP);

  for (int kc = 0; kc < 4; ++kc) {
    bf16* vbuf = KV[kc & 1];
    __syncthreads();                       // drains V(kc); prior MFMA reads done
    if (kc < 3) issueV(kc + 1, KV[(kc & 1) ^ 1]);
#pragma unroll
    for (int j = 0; j < 8; ++j)
#pragma unroll
      for (int r = 0; r < 4; ++r)
        Plw[(quad * 4 + r) * VLP + j * 16 + l15] = (bf16)S[kc][j][r];
    __syncthreads();                       // P visible
#pragma unroll
    for (int ks = 0; ks < 4; ++ks) {
      bf16x8 pa = *(const bf16x8*)(Plw + l15 * VLP + ks * 32 + q8);
#pragma unroll
      for (int n = 0; n < 5; ++n) {
        int d = n * 16 + l15;
        // global chunk (ks*4+quad) lives at LDS chunk ^(d&7)
        int chl = (ks * 4 + quad) ^ (d & 7);
        bf16x8 vb = *(const bf16x8*)(vbuf + d * 128 + chl * 8);
        O[n] = __builtin_amdgcn_mfma_f32_16x16x32_bf16(pa, vb, O[n], 0, 0, 0);
      }
    }
  }

#pragma unroll
  for (int n = 0; n < 5; ++n)
#pragma unroll
    for (int r = 0; r < 4; ++r) {
      int row = tw + quad * 4 + r;
      int col = h * HD + n * 16 + l15;
      out[(size_t)row * D_DIM + col] = (bf16)(O[n][r] / vsum[r]);
    }
}

// ---------------------------------------------------------------------------
extern "C" void kernel_launch(void* const* d_in, const int* in_sizes, int n_in,
                              void* d_out, int out_size, void* d_ws, size_t ws_size,
                              hipStream_t stream)
{
  const float* hidden = (const float*)d_in[0];
  // d_in[1]: cu_seqlens (int32) — fixed 8x512 segments, handled structurally
  const float* rot    = (const float*)d_in[2];
  const float* qkv_w  = (const float*)d_in[3];
  const float* qkv_b  = (const float*)d_in[4];
  const float* proj_w = (const float*)d_in[5];
  const float* proj_b = (const float*)d_in[6];
  float* out = (float*)d_out;

  char* ws = (char*)d_ws;
  bf16* qkvw_bf  = (bf16*)(ws);              //  9,830,400 B [3840][1280]
  bf16* projw_bf = (bf16*)(ws +  9830400);   //  3,276,800 B [1280][1280]
  bf16* hid_bf   = (bf16*)(ws + 13107200);   // 10,485,760 B [4096][1280]
  bf16* attn     = (bf16*)(ws + 13107200);   // reuses hid_bf (dead after K1)
  bf16* Qh       = (bf16*)(ws + 23592960);   // 12,582,912 B [16][4096][96]
  bf16* Kh       = (bf16*)(ws + 36175872);   // 12,582,912 B
  bf16* Vt       = (bf16*)(ws + 48758784);   // 10,485,760 B [16][80][4096]
                                             // total 59,244,544 B

  cvt_all<<<dim3(11520), dim3(256), 0, stream>>>(
      hidden, qkv_w, proj_w, hid_bf, qkvw_bf, projw_bf);
  // K1: qkv GEMM, 32x20 tiles of 128x192, band-swizzled
  gemm128<0, 128, 192><<<dim3(640), dim3(256), 0, stream>>>(
      hid_bf, qkvw_bf, qkv_b, (void*)Qh, Kh, Vt, 3840, 1280, 20);
  // K2: rope (65536 rows x 6 slices)
  rope2<<<dim3(1536), dim3(256), 0, stream>>>(rot, Qh, Kh);
  // K3: block-diagonal attention, XCD-swizzled linear grid
  attn_kernel<<<dim3(1024), dim3(256), 0, stream>>>(Qh, Kh, Vt, attn);
  // K4: proj GEMM, 64x10 tiles of 64x128, fp32 out, A-sharing swizzle
  gemm128<1, 64, 128><<<dim3(640), dim3(256), 0, stream>>>(
      attn, projw_bf, proj_b, (void*)out, nullptr, nullptr, 1280, 1280, 10);
}

// Round 10
// 206.993 us; speedup vs baseline: 1.1461x; 1.0375x over previous
//
#include <hip/hip_runtime.h>
#include <hip/hip_bf16.h>

// ---------------------------------------------------------------------------
// Qwen2VL SDPA attention block, MI355X/gfx950. fp32 in/out, bf16 MFMA inside.
// T=4096, D=1280, H=16, HD=80, 8 segments of 512 (block-diagonal attention).
// Pipeline: [C]  convert hidden/qkv_w/proj_w fp32->bf16 (one fused kernel)
//           [K1] qkv GEMM (128x160 tile, dbuf global_load_lds, 3 blocks/CU,
//                768-block balanced grid) with FUSED ROPE epilogue:
//                Q/K roped in-epilogue -> [h][t][96] (+zero pads),
//                V -> Vt[h][d][t]. BN=160 => each wave-half = one head.
//           [K3] attention: K/V DMA double-buffered, exact softmax,
//                XCD-swizzled grid
//           [K4] out = attn @ proj_w^T + proj_b (BM=64, A-sharing XCD swizzle)
// ---------------------------------------------------------------------------

#define T_DIM 4096
#define D_DIM 1280
#define NH    16
#define HD    80
#define HDP   96      // head dim padded to 3x32 for K=32 MFMA steps
#define SEG   512
#define VLP   136     // P LDS row stride (pad off pow2)
#define RLS   84      // rope-epilogue LDS row stride (quad-spread banks, 8B ok)

typedef __bf16 bf16;
typedef bf16  bf16x4 __attribute__((ext_vector_type(4)));
typedef bf16  bf16x8 __attribute__((ext_vector_type(8)));
typedef float f32x4  __attribute__((ext_vector_type(4)));

__device__ __forceinline__ void gload16(const bf16* g, bf16* l) {
  __builtin_amdgcn_global_load_lds(
      (const __attribute__((address_space(1))) void*)g,
      (__attribute__((address_space(3))) void*)l, 16, 0, 0);
}

// ---------------------------------------------------------------------------
// Fused fp32->bf16 convert of hidden (1310720 f4), qkv_w (1228800 f4),
// proj_w (409600 f4). Grid covers 2949120 float4 groups.
// ---------------------------------------------------------------------------
__global__ __launch_bounds__(256) void cvt_all(
    const float* __restrict__ hid, const float* __restrict__ qw,
    const float* __restrict__ pw, bf16* __restrict__ hb,
    bf16* __restrict__ qwb, bf16* __restrict__ pwb)
{
  int i = blockIdx.x * 256 + threadIdx.x;
  const float* src; bf16* dst; int off;
  if (i < 1310720)      { src = hid; dst = hb;  off = i; }
  else if (i < 2539520) { src = qw;  dst = qwb; off = i - 1310720; }
  else                  { src = pw;  dst = pwb; off = i - 2539520; }
  float4 v = ((const float4*)src)[off];
  ((bf16x4*)dst)[off] = (bf16x4){(bf16)v.x, (bf16)v.y, (bf16)v.z, (bf16)v.w};
}

// ---------------------------------------------------------------------------
// BMxBN-tile GEMM: C = A[M,K] @ W[N,K]^T + bias. BK=32, 4 waves (2x2), each
// wave (BM/2)x(BN/2). Double-buffered LDS via global_load_lds width=16.
// EPI=0 (BM=128,BN=160): wave-half = exactly one head. Q/K tiles: C-tile ->
//   wave-private LDS -> per-row rope (pairs (d,d+40) in-row) -> [h][t][96]
//   with zeroed pads. V tiles: Vt[h][d][T] bf16x4 scatter. Band swizzle.
// EPI=1: A-sharing swizzle (lin%8==mt%8 -> one XCD per A-tile); fp32 store.
// ---------------------------------------------------------------------------
template <int EPI, int BM, int BN>
__global__ __launch_bounds__(256, 3) void gemm128(
    const bf16* __restrict__ A, const bf16* __restrict__ W,
    const float* __restrict__ bias, const float* __restrict__ rot,
    void* __restrict__ out0, bf16* __restrict__ Kh, bf16* __restrict__ Vt,
    int N, int K, int tiles_n)
{
  constexpr int MI = BM / 32;               // m-frags per wave
  constexpr int NJ = BN / 32;               // n-frags per wave
  // LDS: dbuf staging (As 2*BM*32, Bs 2*BN*32) unioned with the rope
  // epilogue buffer (4 waves x 64 x RLS bf16 = 43008 B when BM=128).
  constexpr int STAGE = 2 * (BM + BN) * 32;
  constexpr int EPIB  = (EPI == 0) ? 4 * 64 * RLS : 0;
  constexpr int LDSZ  = (STAGE > EPIB ? STAGE : EPIB);
  __shared__ __align__(16) bf16 smem[LDSZ];
  bf16* As = smem;
  bf16* Bs = smem + 2 * BM * 32;

  int tid  = threadIdx.x;
  int wave = tid >> 6, lane = tid & 63;
  int l15 = lane & 15, quad = lane >> 4, q8 = quad * 8;
  int mt, nt;
  if (EPI == 0) {
    // band swizzle: bands of 8 mt; within a band sweep nt; lin&7 = mt-in-band
    int band = blockIdx.x / (8 * tiles_n);
    int r    = blockIdx.x % (8 * tiles_n);
    nt = r >> 3;
    mt = band * 8 + (r & 7);
  } else {
    // A-sharing swizzle: lin = nt*tiles_m + mt -> lin%8 == mt%8 (same XCD)
    int tiles_m = gridDim.x / tiles_n;
    mt = blockIdx.x % tiles_m;
    nt = blockIdx.x / tiles_m;
  }
  int m0 = mt * BM, n0 = nt * BN;
  int wm = (wave >> 1) * (BM / 2), wn = (wave & 1) * (BN / 2);

  int er  = tid >> 2;
  int ec8 = (tid & 3) * 8;
  const bf16* ga = A + (size_t)(m0 + er) * K + ec8;
  const bf16* gb = W + (size_t)(n0 + er) * K + ec8;

  auto issue = [&](int k, int p) {
    bf16* la = As + p * (BM * 32) + tid * 8;
    bf16* lb = Bs + p * (BN * 32) + tid * 8;
#pragma unroll
    for (int i = 0; i < BM / 64; ++i) gload16(ga + (size_t)i * 64 * K + k, la + i * 2048);
#pragma unroll
    for (int i = 0; i < BN / 64; ++i) gload16(gb + (size_t)i * 64 * K + k, lb + i * 2048);
    if (BN == 160) gload16(gb + (size_t)128 * K + k, lb + 4096);  // rows 128..159: tid<128 half? no:
  };
  // NOTE for BN=160: Bs needs 160 rows * 32 cols. tid*8 covers 2048 elems
  // (64 rows) per 256-thread issue; BN/64 = 2 full issues cover 128 rows;
  // the extra gload above would over-run. Handled below instead.

  f32x4 acc[MI][NJ];
#pragma unroll
  for (int i = 0; i < MI; ++i)
#pragma unroll
    for (int j = 0; j < NJ; ++j) acc[i][j] = (f32x4){0.f, 0.f, 0.f, 0.f};

  // staging for BN=160: B has 160 rows => 160*4 = 640 16B-chunks; threads
  // 0..255 do two chunks, threads 0..127 do a third.
  auto issue160 = [&](int k, int p) {
    bf16* la = As + p * (BM * 32) + tid * 8;
    bf16* lb = Bs + p * (BN * 32) + tid * 8;
    gload16(ga + k, la);
    gload16(ga + (size_t)64 * K + k, la + 2048);
    gload16(gb + k, lb);
    gload16(gb + (size_t)64 * K + k, lb + 2048);
    if (tid < 128) gload16(gb + (size_t)128 * K + k, lb + 4096);
  };
  auto issueN = [&](int k, int p) {
    if (BN == 160) issue160(k, p);
    else           issue(k, p);
  };

  int NK = K / 32;
  issueN(0, 0);
  for (int kt = 0; kt < NK; ++kt) {
    int p = kt & 1;
    __syncthreads();                      // drains DMA(kt) + prev frag reads
    if (kt + 1 < NK) issueN((kt + 1) * 32, p ^ 1);
    bf16x8 af[MI], bfr[NJ];
#pragma unroll
    for (int i = 0; i < MI; ++i)
      af[i] = *(const bf16x8*)(As + p * (BM * 32) + (wm + i * 16 + l15) * 32 + q8);
#pragma unroll
    for (int j = 0; j < NJ; ++j)
      bfr[j] = *(const bf16x8*)(Bs + p * (BN * 32) + (wn + j * 16 + l15) * 32 + q8);
#pragma unroll
    for (int i = 0; i < MI; ++i)
#pragma unroll
      for (int j = 0; j < NJ; ++j)
        acc[i][j] = __builtin_amdgcn_mfma_f32_16x16x32_bf16(af[i], bfr[j], acc[i][j], 0, 0, 0);
  }

  if (EPI == 0) {
    bf16* Qh = (bf16*)out0;
    int c0  = n0 + wn;                 // wave's first col = head base
    int sel = c0 / D_DIM;              // 0=Q, 1=K, 2=V (block-uniform: BN=160 | 1280)
    if (sel < 2) {
      // ---- fused rope epilogue ----
      __syncthreads();                 // all frag reads done; reuse smem
      bf16* Lw = smem + wave * (64 * RLS);
      int cc0 = c0 - sel * D_DIM;
      int h   = cc0 / HD;
#pragma unroll
      for (int j = 0; j < NJ; ++j) {
        float bv = bias[c0 + j * 16 + l15];
#pragma unroll
        for (int i = 0; i < MI; ++i)
#pragma unroll
          for (int r = 0; r < 4; ++r)
            Lw[(i * 16 + quad * 4 + r) * RLS + j * 16 + l15] = (bf16)(acc[i][j][r] + bv);
      }
      __syncthreads();                 // wave-private, but be safe vs reorder
      // lane = local row
      int t = m0 + wm + lane;
      bf16x4 x[20];
#pragma unroll
      for (int a = 0; a < 20; ++a)
        x[a] = *(const bf16x4*)(Lw + lane * RLS + a * 4);
      const float* fp = rot + t * 40;
      float fr[40];
#pragma unroll
      for (int a = 0; a < 10; ++a) {
        float4 f4 = *(const float4*)(fp + a * 4);
        fr[a * 4] = f4.x; fr[a * 4 + 1] = f4.y; fr[a * 4 + 2] = f4.z; fr[a * 4 + 3] = f4.w;
      }
      const float sc = (sel == 0) ? 0.11180339887498949f : 1.0f;
      bf16* dst = ((sel == 0) ? Qh : Kh) + ((size_t)h * T_DIM + t) * HDP;
#pragma unroll
      for (int a = 0; a < 10; ++a) {
        bf16x4 o1, o2;
#pragma unroll
        for (int b = 0; b < 4; ++b) {
          float cs, sn;
          __sincosf(fr[a * 4 + b], &sn, &cs);
          cs *= sc; sn *= sc;
          float xa = (float)x[a][b], xb = (float)x[a + 10][b];
          o1[b] = (bf16)(xa * cs - xb * sn);
          o2[b] = (bf16)(xb * cs + xa * sn);
        }
        *(bf16x4*)(dst + a * 4)      = o1;
        *(bf16x4*)(dst + 40 + a * 4) = o2;
      }
      bf16x8 z = {};
      *(bf16x8*)(dst + 80) = z;
      *(bf16x8*)(dst + 88) = z;
    } else {
      // ---- V scatter (transposed, t-major) ----
#pragma unroll
      for (int j = 0; j < NJ; ++j) {
        int c = c0 + j * 16 + l15;
        float bv = bias[c];
        int cc = c - 2 * D_DIM;
        int h = cc / HD, d = cc - h * HD;
        bf16* vrow = Vt + ((size_t)h * HD + d) * T_DIM;
#pragma unroll
        for (int i = 0; i < MI; ++i) {
          int t0 = m0 + wm + i * 16 + quad * 4;
          bf16x4 pv = {(bf16)(acc[i][j][0] + bv), (bf16)(acc[i][j][1] + bv),
                       (bf16)(acc[i][j][2] + bv), (bf16)(acc[i][j][3] + bv)};
          *(bf16x4*)(vrow + t0) = pv;
        }
      }
    }
  } else {
    float* out = (float*)out0;
#pragma unroll
    for (int j = 0; j < NJ; ++j) {
      int col = n0 + wn + j * 16 + l15;
      float bv = bias[col];
#pragma unroll
      for (int i = 0; i < MI; ++i)
#pragma unroll
        for (int r = 0; r < 4; ++r) {
          int row = m0 + wm + i * 16 + quad * 4 + r;
          out[(size_t)row * N + col] = acc[i][j][r] + bv;
        }
    }
  }
}

// ---------------------------------------------------------------------------
// K3: attention (R5 structure — measured best). Grid 1024 XCD-swizzled
// blocks (lin%8 groups share K/V L2). K/V staged via global_load_lds into
// double buffers; one barrier per QK chunk; V(0) prefetch issued during the
// last QK chunk and drains behind the softmax VALU stretch. V chunks
// XOR-swizzled (chunk ^ (d&7)) so [80][128] pow-2 stride reads stay at the
// bank floor.
// ---------------------------------------------------------------------------
__global__ __launch_bounds__(256, 2) void attn_kernel(
    const bf16* __restrict__ Qh, const bf16* __restrict__ Kh,
    const bf16* __restrict__ Vt, bf16* __restrict__ out)
{
  // KV double buffers 2 x 24576 B (K [128][96] / V [80][128]); P 17408 B
  __shared__ __align__(16) char smem[66560];
  bf16* KV[2] = {(bf16*)smem, (bf16*)(smem + 24576)};
  bf16* Pl    = (bf16*)(smem + 49152);

  int lin  = blockIdx.x;
  int g    = lin & 127;        // (seg,head) group
  int tile = lin >> 7;         // 0..7
  int h    = g & 15;
  int seg  = g >> 4;
  int seg0 = seg * SEG;
  int t0   = seg0 + tile * 64;

  int tid  = threadIdx.x;
  int wave = tid >> 6;
  int lane = tid & 63;
  int l15 = lane & 15, quad = lane >> 4, q8 = quad * 8;
  int tw = t0 + wave * 16;

  const bf16* khbase = Kh + ((size_t)h * T_DIM + seg0) * HDP;
  const bf16* vtbase = Vt + (size_t)h * HD * T_DIM + seg0;

  auto issueK = [&](int kc, bf16* buf) {
    const bf16* src = khbase + (size_t)kc * (128 * HDP);
#pragma unroll
    for (int i = 0; i < 6; ++i)
      gload16(src + (i * 256 + tid) * 8, buf + (i * 256 + tid) * 8);
  };
  auto issueV = [&](int kc, bf16* buf) {
    const bf16* src = vtbase + kc * 128;
#pragma unroll
    for (int i = 0; i < 5; ++i) {
      int idx = i * 256 + tid;            // 0..1279
      int d = idx >> 4, ch = idx & 15;
      int chg = ch ^ (d & 7);             // XOR source-chunk swizzle
      gload16(src + (size_t)d * T_DIM + chg * 8, buf + idx * 8);
    }
  };

  issueK(0, KV[0]);

  bf16x8 qf[3];
  {
    const bf16* qbase = Qh + ((size_t)h * T_DIM + tw + l15) * HDP + q8;
#pragma unroll
    for (int kk = 0; kk < 3; ++kk) qf[kk] = *(const bf16x8*)(qbase + kk * 32);
  }

  // ---- Phase A: S = Q K^T, 4 chunks of 128 keys, 1 barrier/chunk ----
  f32x4 S[4][8];
  for (int kc = 0; kc < 4; ++kc) {
    bf16* buf = KV[kc & 1];
    __syncthreads();                       // drains DMA(kc) + prior reads
    if (kc < 3) issueK(kc + 1, KV[(kc & 1) ^ 1]);
    else        issueV(0, KV[0]);          // KV[0] free (last read chunk 2)
#pragma unroll
    for (int j = 0; j < 8; ++j) {
      f32x4 acc = {0.f, 0.f, 0.f, 0.f};
      const bf16* kb = buf + (j * 16 + l15) * HDP + q8;
#pragma unroll
      for (int kk = 0; kk < 3; ++kk)
        acc = __builtin_amdgcn_mfma_f32_16x16x32_bf16(qf[kk], *(const bf16x8*)(kb + kk * 32), acc, 0, 0, 0);
      S[kc][j] = acc;
    }
  }

  // ---- Softmax (exact; scale pre-folded into Q). V(0) in flight. ----
  float vsum[4];
#pragma unroll
  for (int r = 0; r < 4; ++r) {
    float m = -1e30f;
#pragma unroll
    for (int kc = 0; kc < 4; ++kc)
#pragma unroll
      for (int j = 0; j < 8; ++j) m = fmaxf(m, S[kc][j][r]);
    for (int off = 1; off < 16; off <<= 1) m = fmaxf(m, __shfl_xor(m, off));
    float s = 0.f;
#pragma unroll
    for (int kc = 0; kc < 4; ++kc)
#pragma unroll
      for (int j = 0; j < 8; ++j) {
        float e = __expf(S[kc][j][r] - m);
        S[kc][j][r] = e;
        s += e;
      }
    for (int off = 1; off < 16; off <<= 1) s += __shfl_xor(s, off);
    vsum[r] = s;
  }

  // ---- Phase B: O = P V, 4 chunks, V prefetched one chunk ahead ----
  f32x4 O[5];
#pragma unroll
  for (int n = 0; n < 5; ++n) O[n] = (f32x4){0.f, 0.f, 0.f, 0.f};
  bf16* Plw = Pl + wave * (16 * VLP);

  for (int kc = 0; kc < 4; ++kc) {
    bf16* vbuf = KV[kc & 1];
    __syncthreads();                       // drains V(kc); prior MFMA reads done
    if (kc < 3) issueV(kc + 1, KV[(kc & 1) ^ 1]);
#pragma unroll
    for (int j = 0; j < 8; ++j)
#pragma unroll
      for (int r = 0; r < 4; ++r)
        Plw[(quad * 4 + r) * VLP + j * 16 + l15] = (bf16)S[kc][j][r];
    __syncthreads();                       // P visible
#pragma unroll
    for (int ks = 0; ks < 4; ++ks) {
      bf16x8 pa = *(const bf16x8*)(Plw + l15 * VLP + ks * 32 + q8);
#pragma unroll
      for (int n = 0; n < 5; ++n) {
        int d = n * 16 + l15;
        // global chunk (ks*4+quad) lives at LDS chunk ^(d&7)
        int chl = (ks * 4 + quad) ^ (d & 7);
        bf16x8 vb = *(const bf16x8*)(vbuf + d * 128 + chl * 8);
        O[n] = __builtin_amdgcn_mfma_f32_16x16x32_bf16(pa, vb, O[n], 0, 0, 0);
      }
    }
  }

#pragma unroll
  for (int n = 0; n < 5; ++n)
#pragma unroll
    for (int r = 0; r < 4; ++r) {
      int row = tw + quad * 4 + r;
      int col = h * HD + n * 16 + l15;
      out[(size_t)row * D_DIM + col] = (bf16)(O[n][r] / vsum[r]);
    }
}

// ---------------------------------------------------------------------------
extern "C" void kernel_launch(void* const* d_in, const int* in_sizes, int n_in,
                              void* d_out, int out_size, void* d_ws, size_t ws_size,
                              hipStream_t stream)
{
  const float* hidden = (const float*)d_in[0];
  // d_in[1]: cu_seqlens (int32) — fixed 8x512 segments, handled structurally
  const float* rot    = (const float*)d_in[2];
  const float* qkv_w  = (const float*)d_in[3];
  const float* qkv_b  = (const float*)d_in[4];
  const float* proj_w = (const float*)d_in[5];
  const float* proj_b = (const float*)d_in[6];
  float* out = (float*)d_out;

  char* ws = (char*)d_ws;
  bf16* qkvw_bf  = (bf16*)(ws);              //  9,830,400 B [3840][1280]
  bf16* projw_bf = (bf16*)(ws +  9830400);   //  3,276,800 B [1280][1280]
  bf16* hid_bf   = (bf16*)(ws + 13107200);   // 10,485,760 B [4096][1280]
  bf16* attn     = (bf16*)(ws + 13107200);   // reuses hid_bf (dead after K1)
  bf16* Qh       = (bf16*)(ws + 23592960);   // 12,582,912 B [16][4096][96]
  bf16* Kh       = (bf16*)(ws + 36175872);   // 12,582,912 B
  bf16* Vt       = (bf16*)(ws + 48758784);   // 10,485,760 B [16][80][4096]
                                             // total 59,244,544 B

  cvt_all<<<dim3(11520), dim3(256), 0, stream>>>(
      hidden, qkv_w, proj_w, hid_bf, qkvw_bf, projw_bf);
  // K1: qkv GEMM + fused rope, 32x24 tiles of 128x160, band-swizzled,
  // 768 blocks = exactly 3/CU
  gemm128<0, 128, 160><<<dim3(768), dim3(256), 0, stream>>>(
      hid_bf, qkvw_bf, qkv_b, rot, (void*)Qh, Kh, Vt, 3840, 1280, 24);
  // K3: block-diagonal attention, XCD-swizzled linear grid
  attn_kernel<<<dim3(1024), dim3(256), 0, stream>>>(Qh, Kh, Vt, attn);
  // K4: proj GEMM, 64x10 tiles of 64x128, fp32 out, A-sharing swizzle
  gemm128<1, 64, 128><<<dim3(640), dim3(256), 0, stream>>>(
      attn, projw_bf, proj_b, nullptr, (void*)out, nullptr, nullptr, 1280, 1280, 10);
}